// Round 4
// baseline (132.090 us; speedup 1.0000x reference)
//
#include <hip/hip_runtime.h>
#include <hip/hip_bf16.h>
#include <hip/hip_cooperative_groups.h>
#include <math.h>

namespace cg = cooperative_groups;

// ---------------------------------------------------------------------------
// HybridQuantumLinear, single cooperative kernel.
//   Phase A (pre grid.sync):
//     blocks 0..31: build U (256x256 fixed unitary) -> Bt[512][256] bf16
//                   (row n = 2i+c re/im of output amp i, col j = input amp),
//                   8 waves/block = 8 basis columns each.
//     all blocks:   enc = tanh(x@W_in^T)*pi for own 32 rows -> psi_in
//                   (REAL product state, 256 bf16) into swizzled LDS.
//   grid.sync()
//   Phase B: psi_out = psi_in @ Bt^T via MFMA 16x16x32 (K=256, N=512);
//            P_i = re^2+im^2 ; z_q = sum sign_q(i) P_i ; out = z @ W_out^T.
// Amp index i: bit(7-q) = qubit q. In U-build, i = lane*4 + k.
// ---------------------------------------------------------------------------

typedef __attribute__((ext_vector_type(8))) short bf16x8;
typedef __attribute__((ext_vector_type(4))) float f32x4;

__device__ __forceinline__ float2 shfl_xor_f2(float2 v, int m) {
  float2 r;
  r.x = __shfl_xor(v.x, m, 64);
  r.y = __shfl_xor(v.y, m, 64);
  return r;
}
// acc += u*v (complex)
__device__ __forceinline__ float2 cfma(float2 u, float2 v, float2 acc) {
  acc.x = fmaf(u.x, v.x, fmaf(-u.y, v.y, acc.x));
  acc.y = fmaf(u.x, v.y, fmaf(u.y, v.x, acc.y));
  return acc;
}

// general 2x2 gate on qubit q
__device__ __forceinline__ void apply_gate(float2 (&a)[4], int q, float2 u00,
                                           float2 u01, float2 u10, float2 u11,
                                           int lane) {
  const float2 z0 = make_float2(0.f, 0.f);
  if (q == 7) {  // amp bit 0: pairs (0,1),(2,3)
    float2 n0 = cfma(u00, a[0], cfma(u01, a[1], z0));
    float2 n1 = cfma(u10, a[0], cfma(u11, a[1], z0));
    float2 n2 = cfma(u00, a[2], cfma(u01, a[3], z0));
    float2 n3 = cfma(u10, a[2], cfma(u11, a[3], z0));
    a[0] = n0; a[1] = n1; a[2] = n2; a[3] = n3;
  } else if (q == 6) {  // amp bit 1: pairs (0,2),(1,3)
    float2 n0 = cfma(u00, a[0], cfma(u01, a[2], z0));
    float2 n2 = cfma(u10, a[0], cfma(u11, a[2], z0));
    float2 n1 = cfma(u00, a[1], cfma(u01, a[3], z0));
    float2 n3 = cfma(u10, a[1], cfma(u11, a[3], z0));
    a[0] = n0; a[1] = n1; a[2] = n2; a[3] = n3;
  } else {  // lane bit (5-q)
    int m = 1 << (5 - q);
    bool b = (lane >> (5 - q)) & 1;
    float2 ca = b ? u11 : u00;
    float2 cp = b ? u10 : u01;
    #pragma unroll
    for (int k = 0; k < 4; ++k) {
      float2 p = shfl_xor_f2(a[k], m);
      a[k] = cfma(ca, a[k], cfma(cp, p, z0));
    }
  }
}

// CNOT(control q, target q+1)
__device__ __forceinline__ void apply_cnot(float2 (&a)[4], int q, int lane) {
  if (q <= 4) {
    int m = 1 << (4 - q);
    bool ctrl = (lane >> (5 - q)) & 1;
    #pragma unroll
    for (int k = 0; k < 4; ++k) {
      float2 p = shfl_xor_f2(a[k], m);
      a[k].x = ctrl ? p.x : a[k].x;
      a[k].y = ctrl ? p.y : a[k].y;
    }
  } else if (q == 5) {  // control = lane bit 0, target = k bit 1
    bool ct = lane & 1;
    float2 n0 = ct ? a[2] : a[0];
    float2 n1 = ct ? a[3] : a[1];
    float2 n2 = ct ? a[0] : a[2];
    float2 n3 = ct ? a[1] : a[3];
    a[0] = n0; a[1] = n1; a[2] = n2; a[3] = n3;
  } else {  // q == 6: control = k bit 1, target = k bit 0
    float2 t = a[2]; a[2] = a[3]; a[3] = t;
  }
}

__global__ __launch_bounds__(512, 2) void mega_kernel(
    const float* __restrict__ x, const float* __restrict__ W_in,
    const float* __restrict__ W_out, const float* __restrict__ theta,
    __hip_bfloat16* __restrict__ Bt, float* __restrict__ out) {
  __shared__ float mats[32 * 8];      // fused per-(layer,qubit) gates
  __shared__ char psi_lds[32 * 512];  // 32 rows x 256 bf16, XOR-swizzled
  __shared__ float z_lds[8][32][8];
  __shared__ float z_final[32][8];

  const int tid = threadIdx.x;
  const int lane = tid & 63;
  const int w = tid >> 6;  // wave 0..7
  const int rowbase = blockIdx.x * 32;

  // ================= Phase A1: U-build (blocks 0..31) ======================
  if (blockIdx.x < 32) {
    if (tid < 32) {  // fuse RZ*RY*RX per (layer, qubit)
      int l = tid >> 3, q = tid & 7;
      const float* th = theta + (l * 8 + q) * 3;
      float h1 = 0.5f * th[0], h2 = 0.5f * th[1], h3 = 0.5f * th[2];
      float c1 = cosf(h1), s1 = sinf(h1);
      float c2 = cosf(h2), s2 = sinf(h2);
      float c3 = cosf(h3), s3 = sinf(h3);
      // M = RY*RX
      float m00r = c2 * c1, m00i = s2 * s1;
      float m01r = -s2 * c1, m01i = -c2 * s1;
      float m10r = s2 * c1, m10i = -c2 * s1;
      float m11r = c1 * c2, m11i = -s1 * s2;
      // U = RZ*M: row0 *= (c3 - i s3), row1 *= (c3 + i s3)
      float* o = &mats[tid * 8];
      o[0] = c3 * m00r + s3 * m00i;  o[1] = c3 * m00i - s3 * m00r;
      o[2] = c3 * m01r + s3 * m01i;  o[3] = c3 * m01i - s3 * m01r;
      o[4] = c3 * m10r - s3 * m10i;  o[5] = c3 * m10i + s3 * m10r;
      o[6] = c3 * m11r - s3 * m11i;  o[7] = c3 * m11i + s3 * m11r;
    }
    __syncthreads();

    const int j = blockIdx.x * 8 + w;  // basis column 0..255
    float2 a[4];
    #pragma unroll
    for (int k = 0; k < 4; ++k)
      a[k] = make_float2((lane * 4 + k == j) ? 1.f : 0.f, 0.f);

    #pragma unroll
    for (int l = 0; l < 4; ++l) {
      #pragma unroll
      for (int q = 0; q < 8; ++q) {
        const float* m = &mats[(l * 8 + q) * 8];
        float2 u00 = make_float2(m[0], m[1]);
        float2 u01 = make_float2(m[2], m[3]);
        float2 u10 = make_float2(m[4], m[5]);
        float2 u11 = make_float2(m[6], m[7]);
        apply_gate(a, q, u00, u01, u10, u11, lane);
      }
      #pragma unroll
      for (int i = (l & 1); i < 7; i += 2) apply_cnot(a, i, lane);
    }
    #pragma unroll
    for (int k = 0; k < 4; ++k) {
      int n0 = (lane * 4 + k) * 2;
      Bt[n0 * 256 + j]       = __float2bfloat16(a[k].x);
      Bt[(n0 + 1) * 256 + j] = __float2bfloat16(a[k].y);
    }
  }

  // ================= Phase A2: encoding (all blocks, 4 rows/wave) ==========
  {
    const float4* W4 = (const float4*)W_in;
    float4 Wa[8], Wb[8];
    #pragma unroll
    for (int q = 0; q < 8; ++q) {
      Wa[q] = W4[q * 128 + lane];
      Wb[q] = W4[q * 128 + 64 + lane];
    }

    #pragma unroll
    for (int rr = 0; rr < 4; ++rr) {
      const int r = w * 4 + rr;  // row within block 0..31
      const float4* x4 = (const float4*)(x + (size_t)(rowbase + r) * 512);
      float4 xa = x4[lane], xb = x4[64 + lane];
      float acc[8];
      #pragma unroll
      for (int q = 0; q < 8; ++q) {
        acc[q] = xa.x * Wa[q].x + xa.y * Wa[q].y + xa.z * Wa[q].z +
                 xa.w * Wa[q].w + xb.x * Wb[q].x + xb.y * Wb[q].y +
                 xb.z * Wb[q].z + xb.w * Wb[q].w;
      }
      #pragma unroll
      for (int m = 1; m < 64; m <<= 1)
        #pragma unroll
        for (int q = 0; q < 8; ++q) acc[q] += __shfl_xor(acc[q], m, 64);

      float cq[8], sq[8];
      #pragma unroll
      for (int q = 0; q < 8; ++q) {
        float e  = __expf(2.f * acc[q]);
        float th = 1.f - __fdividef(2.f, e + 1.f);  // tanh
        float h  = 1.57079632679489662f * th;       // (pi/2) * tanh
        cq[q] = __cosf(h);
        sq[q] = __sinf(h);
      }
      float base = 1.f;
      #pragma unroll
      for (int q = 0; q < 6; ++q)
        base *= ((lane >> (5 - q)) & 1) ? sq[q] : cq[q];

      __hip_bfloat16 h4[4];
      h4[0] = __float2bfloat16(base * cq[6] * cq[7]);
      h4[1] = __float2bfloat16(base * cq[6] * sq[7]);
      h4[2] = __float2bfloat16(base * sq[6] * cq[7]);
      h4[3] = __float2bfloat16(base * sq[6] * sq[7]);
      int byte = r * 512 + ((lane * 8) ^ ((r & 7) << 4));
      *(uint2*)(psi_lds + byte) = *(uint2*)h4;
    }
  }

  __syncthreads();
  __threadfence();          // make Bt visible device-wide before the barrier
  cg::this_grid().sync();

  // ================= Phase B: GEMM + expval + out-GEMM =====================
  const int cl = lane & 15;  // col-lane / A-row lane
  const int kg = lane >> 4;  // k-group
  const int wcol = w * 64;   // this wave's 64 output cols

  bf16x8 Af[2][8];
  #pragma unroll
  for (int rt = 0; rt < 2; ++rt)
    #pragma unroll
    for (int kb = 0; kb < 8; ++kb) {
      int row = rt * 16 + cl;
      int byte = row * 512 + ((kg * 16 + kb * 64) ^ ((row & 7) << 4));
      Af[rt][kb] = *(const bf16x8*)(psi_lds + byte);
    }

  f32x4 acc2[2][4];
  #pragma unroll
  for (int rt = 0; rt < 2; ++rt)
    #pragma unroll
    for (int ct = 0; ct < 4; ++ct) acc2[rt][ct] = (f32x4){0.f, 0.f, 0.f, 0.f};

  const short* Bts = (const short*)Bt;
  #pragma unroll
  for (int kb = 0; kb < 8; ++kb) {
    #pragma unroll
    for (int ct = 0; ct < 4; ++ct) {
      bf16x8 bf = *(const bf16x8*)(Bts +
          (size_t)(wcol + ct * 16 + cl) * 256 + kg * 8 + kb * 32);
      acc2[0][ct] = __builtin_amdgcn_mfma_f32_16x16x32_bf16(Af[0][kb], bf,
                                                            acc2[0][ct], 0, 0, 0);
      acc2[1][ct] = __builtin_amdgcn_mfma_f32_16x16x32_bf16(Af[1][kb], bf,
                                                            acc2[1][ct], 0, 0, 0);
    }
  }

  // ---- epilogue: P_i = re^2+im^2 ; z_q += sign*P. Even lanes q0..3 (high
  // nibble of i), odd lanes q4..7 (low nibble); partner lane has the other
  // component of the same i.
  float zacc[2][4][4];
  #pragma unroll
  for (int rt = 0; rt < 2; ++rt)
    #pragma unroll
    for (int u = 0; u < 4; ++u)
      #pragma unroll
      for (int jr = 0; jr < 4; ++jr) zacc[rt][u][jr] = 0.f;

  #pragma unroll
  for (int ct = 0; ct < 4; ++ct) {
    int n = wcol + ct * 16 + cl;
    int i = n >> 1;
    int ib = (lane & 1) ? (i & 15) : (i >> 4);
    float s[4];
    #pragma unroll
    for (int u = 0; u < 4; ++u)
      s[u] = ((ib >> (3 - u)) & 1) ? -1.f : 1.f;
    #pragma unroll
    for (int rt = 0; rt < 2; ++rt) {
      #pragma unroll
      for (int jr = 0; jr < 4; ++jr) {
        float v = acc2[rt][ct][jr];
        v = v * v;
        float P = v + __shfl_xor(v, 1, 64);
        #pragma unroll
        for (int u = 0; u < 4; ++u)
          zacc[rt][u][jr] = fmaf(s[u], P, zacc[rt][u][jr]);
      }
    }
  }

  #pragma unroll
  for (int m = 2; m <= 8; m <<= 1)
    #pragma unroll
    for (int rt = 0; rt < 2; ++rt)
      #pragma unroll
      for (int u = 0; u < 4; ++u)
        #pragma unroll
        for (int jr = 0; jr < 4; ++jr)
          zacc[rt][u][jr] += __shfl_xor(zacc[rt][u][jr], m, 64);

  if (cl <= 1) {
    #pragma unroll
    for (int rt = 0; rt < 2; ++rt)
      #pragma unroll
      for (int u = 0; u < 4; ++u)
        #pragma unroll
        for (int jr = 0; jr < 4; ++jr)
          z_lds[w][rt * 16 + kg * 4 + jr][(lane & 1) * 4 + u] = zacc[rt][u][jr];
  }
  __syncthreads();

  if (tid < 256) {  // sum the 8 wave partials
    int r = tid >> 3, q = tid & 7;
    float s = 0.f;
    #pragma unroll
    for (int wv = 0; wv < 8; ++wv) s += z_lds[wv][r][q];
    z_final[r][q] = s;
  }
  __syncthreads();

  // ---- out = z @ W_out^T : thread t -> col t --------------------------------
  float4 wa = *(const float4*)(W_out + (size_t)tid * 8);
  float4 wb = *(const float4*)(W_out + (size_t)tid * 8 + 4);
  #pragma unroll 4
  for (int r = 0; r < 32; ++r) {
    float4 z0 = *(const float4*)&z_final[r][0];
    float4 z1 = *(const float4*)&z_final[r][4];
    float d = wa.x * z0.x + wa.y * z0.y + wa.z * z0.z + wa.w * z0.w +
              wb.x * z1.x + wb.y * z1.y + wb.z * z1.z + wb.w * z1.w;
    out[(size_t)(rowbase + r) * 512 + tid] = d;
  }
}

extern "C" void kernel_launch(void* const* d_in, const int* in_sizes, int n_in,
                              void* d_out, int out_size, void* d_ws, size_t ws_size,
                              hipStream_t stream) {
  const float* x     = (const float*)d_in[0];  // (B, 512)
  const float* W_in  = (const float*)d_in[1];  // (8, 512)
  const float* W_out = (const float*)d_in[2];  // (512, 8)
  const float* theta = (const float*)d_in[3];  // (4, 8, 3)
  float* out = (float*)d_out;
  __hip_bfloat16* Bt = (__hip_bfloat16*)d_ws;  // 512*256 bf16 = 256 KiB

  void* args[] = {(void*)&x, (void*)&W_in, (void*)&W_out, (void*)&theta,
                  (void*)&Bt, (void*)&out};
  hipLaunchCooperativeKernel((const void*)mega_kernel, dim3(256), dim3(512),
                             args, 0, stream);
}

// Round 5
// 35.839 us; speedup vs baseline: 3.6856x; 3.6856x over previous
//
#include <hip/hip_runtime.h>
#include <hip/hip_bf16.h>
#include <math.h>

// ---------------------------------------------------------------------------
// HybridQuantumLinear via fixed-unitary GEMM.
//   k01: blocks 0..63 build U (256x256 fixed unitary) -> Bt[512][256] bf16
//        (row n = 2i+c re/im of output amp i, col j = input amp);
//        blocks 64.. encode: enc=tanh(x@W_in^T)*pi -> psi_in (REAL product
//        state, 256 bf16/row) to global. One wave per batch row.
//   k2:  256 blocks x 8 waves; block = 32 batch rows; wave = 64 output cols.
//        psi_out = psi_in @ Bt^T via MFMA 16x16x32 (K=256, N=512);
//        P_i = re^2+im^2 ; z_q = sum sign_q(i) P_i ; out = z @ W_out^T.
// Amp index i: bit(7-q) = qubit q. In U-build, i = lane*4 + k.
// ---------------------------------------------------------------------------

typedef __attribute__((ext_vector_type(8))) short bf16x8;
typedef __attribute__((ext_vector_type(4))) float f32x4;

__device__ __forceinline__ float2 shfl_xor_f2(float2 v, int m) {
  float2 r;
  r.x = __shfl_xor(v.x, m, 64);
  r.y = __shfl_xor(v.y, m, 64);
  return r;
}
// acc += u*v (complex)
__device__ __forceinline__ float2 cfma(float2 u, float2 v, float2 acc) {
  acc.x = fmaf(u.x, v.x, fmaf(-u.y, v.y, acc.x));
  acc.y = fmaf(u.x, v.y, fmaf(u.y, v.x, acc.y));
  return acc;
}

// general 2x2 gate on qubit q
__device__ __forceinline__ void apply_gate(float2 (&a)[4], int q, float2 u00,
                                           float2 u01, float2 u10, float2 u11,
                                           int lane) {
  const float2 z0 = make_float2(0.f, 0.f);
  if (q == 7) {  // amp bit 0: pairs (0,1),(2,3)
    float2 n0 = cfma(u00, a[0], cfma(u01, a[1], z0));
    float2 n1 = cfma(u10, a[0], cfma(u11, a[1], z0));
    float2 n2 = cfma(u00, a[2], cfma(u01, a[3], z0));
    float2 n3 = cfma(u10, a[2], cfma(u11, a[3], z0));
    a[0] = n0; a[1] = n1; a[2] = n2; a[3] = n3;
  } else if (q == 6) {  // amp bit 1: pairs (0,2),(1,3)
    float2 n0 = cfma(u00, a[0], cfma(u01, a[2], z0));
    float2 n2 = cfma(u10, a[0], cfma(u11, a[2], z0));
    float2 n1 = cfma(u00, a[1], cfma(u01, a[3], z0));
    float2 n3 = cfma(u10, a[1], cfma(u11, a[3], z0));
    a[0] = n0; a[1] = n1; a[2] = n2; a[3] = n3;
  } else {  // lane bit (5-q)
    int m = 1 << (5 - q);
    bool b = (lane >> (5 - q)) & 1;
    float2 ca = b ? u11 : u00;
    float2 cp = b ? u10 : u01;
    #pragma unroll
    for (int k = 0; k < 4; ++k) {
      float2 p = shfl_xor_f2(a[k], m);
      a[k] = cfma(ca, a[k], cfma(cp, p, z0));
    }
  }
}

// CNOT(control q, target q+1)
__device__ __forceinline__ void apply_cnot(float2 (&a)[4], int q, int lane) {
  if (q <= 4) {
    int m = 1 << (4 - q);
    bool ctrl = (lane >> (5 - q)) & 1;
    #pragma unroll
    for (int k = 0; k < 4; ++k) {
      float2 p = shfl_xor_f2(a[k], m);
      a[k].x = ctrl ? p.x : a[k].x;
      a[k].y = ctrl ? p.y : a[k].y;
    }
  } else if (q == 5) {  // control = lane bit 0, target = k bit 1
    bool ct = lane & 1;
    float2 n0 = ct ? a[2] : a[0];
    float2 n1 = ct ? a[3] : a[1];
    float2 n2 = ct ? a[0] : a[2];
    float2 n3 = ct ? a[1] : a[3];
    a[0] = n0; a[1] = n1; a[2] = n2; a[3] = n3;
  } else {  // q == 6: control = k bit 1, target = k bit 0
    float2 t = a[2]; a[2] = a[3]; a[3] = t;
  }
}

__global__ __launch_bounds__(256) void k01_kernel(
    const float* __restrict__ x, const float* __restrict__ W_in,
    const float* __restrict__ theta, __hip_bfloat16* __restrict__ Bt,
    __hip_bfloat16* __restrict__ psi, int psi_stride, int B) {
  __shared__ float mats[32 * 8];
  const int tid = threadIdx.x;
  const int lane = tid & 63;

  if (blockIdx.x < 64) {
    // ---------------- U-build: fused gate matrices, then basis-state sim ----
    if (tid < 32) {
      int l = tid >> 3, q = tid & 7;
      const float* th = theta + (l * 8 + q) * 3;
      float h1 = 0.5f * th[0], h2 = 0.5f * th[1], h3 = 0.5f * th[2];
      float c1 = cosf(h1), s1 = sinf(h1);
      float c2 = cosf(h2), s2 = sinf(h2);
      float c3 = cosf(h3), s3 = sinf(h3);
      // M = RY*RX
      float m00r = c2 * c1, m00i = s2 * s1;
      float m01r = -s2 * c1, m01i = -c2 * s1;
      float m10r = s2 * c1, m10i = -c2 * s1;
      float m11r = c1 * c2, m11i = -s1 * s2;
      // U = RZ*M: row0 *= (c3 - i s3), row1 *= (c3 + i s3)
      float* o = &mats[tid * 8];
      o[0] = c3 * m00r + s3 * m00i;  o[1] = c3 * m00i - s3 * m00r;
      o[2] = c3 * m01r + s3 * m01i;  o[3] = c3 * m01i - s3 * m01r;
      o[4] = c3 * m10r - s3 * m10i;  o[5] = c3 * m10i + s3 * m10r;
      o[6] = c3 * m11r - s3 * m11i;  o[7] = c3 * m11i + s3 * m11r;
    }
    __syncthreads();

    const int j = blockIdx.x * 4 + (tid >> 6);  // basis column 0..255
    float2 a[4];
    #pragma unroll
    for (int k = 0; k < 4; ++k)
      a[k] = make_float2((lane * 4 + k == j) ? 1.f : 0.f, 0.f);

    #pragma unroll
    for (int l = 0; l < 4; ++l) {
      #pragma unroll
      for (int q = 0; q < 8; ++q) {
        const float* m = &mats[(l * 8 + q) * 8];
        float2 u00 = make_float2(m[0], m[1]);
        float2 u01 = make_float2(m[2], m[3]);
        float2 u10 = make_float2(m[4], m[5]);
        float2 u11 = make_float2(m[6], m[7]);
        apply_gate(a, q, u00, u01, u10, u11, lane);
      }
      #pragma unroll
      for (int i = (l & 1); i < 7; i += 2) apply_cnot(a, i, lane);
    }
    // Bt[n][j], n = 2i + c, i = lane*4 + k  (row-major 512 x 256)
    #pragma unroll
    for (int k = 0; k < 4; ++k) {
      int n0 = (lane * 4 + k) * 2;
      Bt[n0 * 256 + j]       = __float2bfloat16(a[k].x);
      Bt[(n0 + 1) * 256 + j] = __float2bfloat16(a[k].y);
    }
    return;
  }

  // ---------------- encoding + psi_in ----------------
  const int b = (int)(blockIdx.x - 64) * 4 + (tid >> 6);
  if (b >= B) return;

  float xv[8];
  #pragma unroll
  for (int j = 0; j < 8; ++j) xv[j] = x[b * 512 + j * 64 + lane];

  float acc[8];
  #pragma unroll
  for (int q = 0; q < 8; ++q) {
    float s = 0.f;
    #pragma unroll
    for (int j = 0; j < 8; ++j)
      s = fmaf(xv[j], W_in[q * 512 + j * 64 + lane], s);
    acc[q] = s;
  }
  #pragma unroll
  for (int m = 1; m < 64; m <<= 1) {
    #pragma unroll
    for (int q = 0; q < 8; ++q) acc[q] += __shfl_xor(acc[q], m, 64);
  }

  float cq[8], sq[8];
  #pragma unroll
  for (int q = 0; q < 8; ++q) {
    float e  = __expf(2.f * acc[q]);
    float th = 1.f - __fdividef(2.f, e + 1.f);  // tanh
    float h  = 1.57079632679489662f * th;       // (pi/2) * tanh
    cq[q] = __cosf(h);
    sq[q] = __sinf(h);
  }

  float base = 1.f;
  #pragma unroll
  for (int q = 0; q < 6; ++q)
    base *= ((lane >> (5 - q)) & 1) ? sq[q] : cq[q];

  float a0 = base * cq[6] * cq[7];
  float a1 = base * cq[6] * sq[7];
  float a2 = base * sq[6] * cq[7];
  float a3 = base * sq[6] * sq[7];

  __hip_bfloat16 h4[4] = {__float2bfloat16(a0), __float2bfloat16(a1),
                          __float2bfloat16(a2), __float2bfloat16(a3)};
  uint2 pk = *reinterpret_cast<uint2*>(h4);
  *reinterpret_cast<uint2*>(psi + (size_t)b * psi_stride + lane * 4) = pk;
}

__global__ __launch_bounds__(512, 2) void k2_kernel(
    const __hip_bfloat16* __restrict__ psi, const __hip_bfloat16* __restrict__ Bt,
    const float* __restrict__ W_out, float* __restrict__ out, int psi_stride) {
  __shared__ float z_lds[8][32][8];
  __shared__ float z_final[32][8];
  const int tid = threadIdx.x;
  const int lane = tid & 63;
  const int w = tid >> 6;        // wave 0..7
  const int rowbase = blockIdx.x * 32;
  const int cl = lane & 15;      // col-lane / A-row lane
  const int kg = lane >> 4;      // k-group
  const int wcol = w * 64;       // this wave's 64 output cols

  const short* psis = (const short*)psi;
  const short* Bts  = (const short*)Bt;

  // A fragments: A[row][k] = psi_in, row = rowbase + rt*16 + cl
  bf16x8 Af[2][8];
  #pragma unroll
  for (int rt = 0; rt < 2; ++rt)
    #pragma unroll
    for (int kb = 0; kb < 8; ++kb)
      Af[rt][kb] = *(const bf16x8*)(psis +
          (size_t)(rowbase + rt * 16 + cl) * psi_stride + kb * 32 + kg * 8);

  f32x4 acc2[2][4];
  #pragma unroll
  for (int rt = 0; rt < 2; ++rt)
    #pragma unroll
    for (int ct = 0; ct < 4; ++ct) acc2[rt][ct] = (f32x4){0.f, 0.f, 0.f, 0.f};

  #pragma unroll
  for (int kb = 0; kb < 8; ++kb) {
    #pragma unroll
    for (int ct = 0; ct < 4; ++ct) {
      bf16x8 bf = *(const bf16x8*)(Bts +
          (size_t)(wcol + ct * 16 + cl) * 256 + kg * 8 + kb * 32);
      acc2[0][ct] = __builtin_amdgcn_mfma_f32_16x16x32_bf16(Af[0][kb], bf,
                                                            acc2[0][ct], 0, 0, 0);
      acc2[1][ct] = __builtin_amdgcn_mfma_f32_16x16x32_bf16(Af[1][kb], bf,
                                                            acc2[1][ct], 0, 0, 0);
    }
  }

  // ---- epilogue: P_i = re^2+im^2 ; z_q += sign*P. Even lanes q0..3 (high
  // nibble of i), odd lanes q4..7 (low nibble); partner lane has the other
  // component of the same i.
  float zacc[2][4][4];
  #pragma unroll
  for (int rt = 0; rt < 2; ++rt)
    #pragma unroll
    for (int u = 0; u < 4; ++u)
      #pragma unroll
      for (int jr = 0; jr < 4; ++jr) zacc[rt][u][jr] = 0.f;

  #pragma unroll
  for (int ct = 0; ct < 4; ++ct) {
    int n = wcol + ct * 16 + cl;
    int i = n >> 1;
    int ib = (lane & 1) ? (i & 15) : (i >> 4);
    float s[4];
    #pragma unroll
    for (int u = 0; u < 4; ++u)
      s[u] = ((ib >> (3 - u)) & 1) ? -1.f : 1.f;
    #pragma unroll
    for (int rt = 0; rt < 2; ++rt) {
      #pragma unroll
      for (int jr = 0; jr < 4; ++jr) {
        float v = acc2[rt][ct][jr];
        v = v * v;
        float P = v + __shfl_xor(v, 1, 64);
        #pragma unroll
        for (int u = 0; u < 4; ++u)
          zacc[rt][u][jr] = fmaf(s[u], P, zacc[rt][u][jr]);
      }
    }
  }

  #pragma unroll
  for (int m = 2; m <= 8; m <<= 1)
    #pragma unroll
    for (int rt = 0; rt < 2; ++rt)
      #pragma unroll
      for (int u = 0; u < 4; ++u)
        #pragma unroll
        for (int jr = 0; jr < 4; ++jr)
          zacc[rt][u][jr] += __shfl_xor(zacc[rt][u][jr], m, 64);

  if (cl <= 1) {
    #pragma unroll
    for (int rt = 0; rt < 2; ++rt)
      #pragma unroll
      for (int u = 0; u < 4; ++u)
        #pragma unroll
        for (int jr = 0; jr < 4; ++jr)
          z_lds[w][rt * 16 + kg * 4 + jr][(lane & 1) * 4 + u] = zacc[rt][u][jr];
  }
  __syncthreads();

  if (tid < 256) {  // sum the 8 wave partials
    int r = tid >> 3, q = tid & 7;
    float s = 0.f;
    #pragma unroll
    for (int wv = 0; wv < 8; ++wv) s += z_lds[wv][r][q];
    z_final[r][q] = s;
  }
  __syncthreads();

  // ---- out = z @ W_out^T : thread t -> col t --------------------------------
  float4 wa = *(const float4*)(W_out + (size_t)tid * 8);
  float4 wb = *(const float4*)(W_out + (size_t)tid * 8 + 4);
  #pragma unroll 4
  for (int r = 0; r < 32; ++r) {
    float4 z0 = *(const float4*)&z_final[r][0];
    float4 z1 = *(const float4*)&z_final[r][4];
    float d = wa.x * z0.x + wa.y * z0.y + wa.z * z0.z + wa.w * z0.w +
              wb.x * z1.x + wb.y * z1.y + wb.z * z1.z + wb.w * z1.w;
    out[(size_t)(rowbase + r) * 512 + tid] = d;
  }
}

extern "C" void kernel_launch(void* const* d_in, const int* in_sizes, int n_in,
                              void* d_out, int out_size, void* d_ws, size_t ws_size,
                              hipStream_t stream) {
  const float* x     = (const float*)d_in[0];  // (B, 512)
  const float* W_in  = (const float*)d_in[1];  // (8, 512)
  const float* W_out = (const float*)d_in[2];  // (512, 8)
  const float* theta = (const float*)d_in[3];  // (4, 8, 3)
  float* out = (float*)d_out;

  const int B = in_sizes[0] / 512;  // 8192
  const size_t btBytes  = 512 * 256 * sizeof(__hip_bfloat16);  // 256 KiB
  const size_t psiBytes = (size_t)B * 256 * sizeof(__hip_bfloat16);

  __hip_bfloat16* Bt = (__hip_bfloat16*)d_ws;
  __hip_bfloat16* psi;
  int psi_stride;
  if (ws_size >= btBytes + psiBytes) {
    psi = (__hip_bfloat16*)((char*)d_ws + btBytes);
    psi_stride = 256;
  } else {
    // overlay psi inside d_out: psi row b occupies the first 512 B of out
    // row b (out row = 2048 B). k2 reads its own rows before the barrier
    // that precedes its out-writes, so this is race-free.
    psi = (__hip_bfloat16*)d_out;
    psi_stride = 1024;
  }

  hipLaunchKernelGGL(k01_kernel, dim3(64 + B / 4), dim3(256), 0, stream,
                     x, W_in, theta, Bt, psi, psi_stride, B);
  hipLaunchKernelGGL(k2_kernel, dim3(B / 32), dim3(512), 0, stream,
                     psi, Bt, W_out, out, psi_stride);
}